// Round 4
// baseline (1112.181 us; speedup 1.0000x reference)
//
#include <hip/hip_runtime.h>
#include <stdint.h>

#define B_ 1024
#define T_ 512
#define F_ 64
#define H_ 32
#define G_ 128  // 4H

__device__ __forceinline__ uint32_t bf16r(float f) {
  uint32_t u = __builtin_bit_cast(uint32_t, f);
  return (u + 0x7fffu + ((u >> 16) & 1u)) >> 16;  // RNE bf16
}
__device__ __forceinline__ float rl(float v, int l) {
  return __builtin_bit_cast(float, __builtin_amdgcn_readlane(__builtin_bit_cast(int, v), l));
}
__device__ __forceinline__ float fsig(float x) { return 1.f / (1.f + __expf(-x)); }
__device__ __forceinline__ float ftanh(float x) { return 2.f / (1.f + __expf(-2.f * x)) - 1.f; }
__device__ __forceinline__ float bflo(uint32_t d) { return __builtin_bit_cast(float, d << 16); }
__device__ __forceinline__ float bfhi(uint32_t d) { return __builtin_bit_cast(float, d & 0xffff0000u); }

// ---------------------------------------------------------------------------
// K1: unchanged (known good). xg[b][t][j] = pack_bf16(G[j], G[j+64])
// ---------------------------------------------------------------------------
__global__ __launch_bounds__(256, 1) void k1_encxg(
    const float* __restrict__ x, const float* __restrict__ Wenc,
    const float* __restrict__ benc, const float* __restrict__ kern,
    const float* __restrict__ bias, uint32_t* __restrict__ xg) {
  __shared__ float sW[F_ * F_];     // 16 KB
  __shared__ float sK[F_ * G_];     // 32 KB
  __shared__ float sX[F_ * 257];    // 65.8 KB, transposed x tile [k][row], pad 257
  const int tid = threadIdx.x;

  for (int i = tid; i < F_ * F_; i += 256) sW[i] = Wenc[i];
  for (int i = tid; i < F_ * G_; i += 256) sK[i] = kern[i];

  const int r0 = blockIdx.x * 256;  // row = b*512 + t
  const float4* x4 = (const float4*)(x + (size_t)r0 * F_);
  for (int i4 = tid; i4 < 256 * F_ / 4; i4 += 256) {
    float4 v = x4[i4];
    int r = i4 >> 4;
    int k0 = (i4 & 15) * 4;
    sX[(k0 + 0) * 257 + r] = v.x;
    sX[(k0 + 1) * 257 + r] = v.y;
    sX[(k0 + 2) * 257 + r] = v.z;
    sX[(k0 + 3) * 257 + r] = v.w;
  }
  __syncthreads();

  float enc[F_];
#pragma unroll
  for (int j4 = 0; j4 < 16; ++j4) {
    float4 b = ((const float4*)benc)[j4];
    enc[j4 * 4 + 0] = b.x; enc[j4 * 4 + 1] = b.y;
    enc[j4 * 4 + 2] = b.z; enc[j4 * 4 + 3] = b.w;
  }
  for (int k = 0; k < F_; ++k) {
    float xk = sX[k * 257 + tid];
#pragma unroll
    for (int j4 = 0; j4 < 16; ++j4) {
      float4 w = *(const float4*)(&sW[k * F_ + j4 * 4]);
      enc[j4 * 4 + 0] += xk * w.x; enc[j4 * 4 + 1] += xk * w.y;
      enc[j4 * 4 + 2] += xk * w.z; enc[j4 * 4 + 3] += xk * w.w;
    }
  }
#pragma unroll
  for (int j = 0; j < F_; ++j) enc[j] = ftanh(enc[j]);

#pragma unroll
  for (int j = 0; j < F_; ++j) sX[j * 257 + tid] = enc[j];
  __syncthreads();

  float acc[G_];
#pragma unroll
  for (int n4 = 0; n4 < 32; ++n4) {
    float4 b = ((const float4*)bias)[n4];
    acc[n4 * 4 + 0] = b.x; acc[n4 * 4 + 1] = b.y;
    acc[n4 * 4 + 2] = b.z; acc[n4 * 4 + 3] = b.w;
  }
  for (int j = 0; j < F_; ++j) {
    float ej = sX[j * 257 + tid];
#pragma unroll
    for (int n4 = 0; n4 < 32; ++n4) {
      float4 w = *(const float4*)(&sK[j * G_ + n4 * 4]);
      acc[n4 * 4 + 0] += ej * w.x; acc[n4 * 4 + 1] += ej * w.y;
      acc[n4 * 4 + 2] += ej * w.z; acc[n4 * 4 + 3] += ej * w.w;
    }
  }

  uint32_t* op = xg + (size_t)(r0 + tid) * 64;
#pragma unroll
  for (int q = 0; q < 16; ++q) {
    uint4 o;
    o.x = bf16r(acc[q * 4 + 0]) | (bf16r(acc[q * 4 + 0 + 64]) << 16);
    o.y = bf16r(acc[q * 4 + 1]) | (bf16r(acc[q * 4 + 1 + 64]) << 16);
    o.z = bf16r(acc[q * 4 + 2]) | (bf16r(acc[q * 4 + 2 + 64]) << 16);
    o.w = bf16r(acc[q * 4 + 3]) | (bf16r(acc[q * 4 + 3 + 64]) << 16);
    ((uint4*)op)[q] = o;
  }
}

// ---------------------------------------------------------------------------
// K2: LSTM scan only. One wave per batch. 4-way split z accumulators.
// f/o exchange via __shfl(act, lane|32) — round-1-verified (ds_bpermute).
// h_t stored FP32 (128B) into the first half of the consumed 256B xg slot.
// ---------------------------------------------------------------------------
__global__ __launch_bounds__(64, 1) void k2_scan(
    uint32_t* xg, const float* __restrict__ rec) {
  const int lane = threadIdx.x;
  const int b = blockIdx.x;
  const bool lo32 = (lane < 32);

  float rA[H_], rB[H_];
#pragma unroll
  for (int k = 0; k < H_; ++k) {
    rA[k] = rec[k * G_ + lane];        // columns 0..63   (i|f)
    rB[k] = rec[k * G_ + 64 + lane];   // columns 64..127 (g|o)
  }

  uint32_t* xp = xg + (size_t)b * (T_ * 64) + lane;
  float* hst = (float*)(xg + (size_t)b * (T_ * 64));

  float h = 0.f, c = 0.f;

  auto step = [&](uint32_t w, int t) {
    float z1a = bflo(w);   // z[lane]       (i|f pre-act)
    float z2a = bfhi(w);   // z[lane+64]    (g|o pre-act)
    float z1b = 0.f, z1c = 0.f, z1d = 0.f;
    float z2b = 0.f, z2c = 0.f, z2d = 0.f;
#pragma unroll
    for (int k4 = 0; k4 < 8; ++k4) {
      float s0 = rl(h, 4 * k4 + 0);
      float s1 = rl(h, 4 * k4 + 1);
      float s2 = rl(h, 4 * k4 + 2);
      float s3 = rl(h, 4 * k4 + 3);
      z1a += s0 * rA[4 * k4 + 0];  z2a += s0 * rB[4 * k4 + 0];
      z1b += s1 * rA[4 * k4 + 1];  z2b += s1 * rB[4 * k4 + 1];
      z1c += s2 * rA[4 * k4 + 2];  z2c += s2 * rB[4 * k4 + 2];
      z1d += s3 * rA[4 * k4 + 3];  z2d += s3 * rB[4 * k4 + 3];
    }
    float z1 = (z1a + z1b) + (z1c + z1d);
    float z2 = (z2a + z2b) + (z2c + z2d);

    float act1 = fsig(z1);                       // i (lanes<32) | f (lanes>=32)
    float xx = lo32 ? 2.f * z2 : z2;
    float sg = fsig(xx);
    float act2 = lo32 ? 2.f * sg - 1.f : sg;     // tanh(g) | sigmoid(o)

    float f_all = __shfl(act1, lane | 32);       // f on all lanes (verified r1)
    float o_all = __shfl(act2, lane | 32);       // o on all lanes

    c = f_all * c + act1 * act2;                 // valid on lanes<32
    float tc = ftanh(c);
    h = o_all * tc;

    if (lo32) hst[(size_t)t * 64 + lane] = h;    // fp32 h into dead slot region
  };

  uint32_t c0 = xp[0 * 64], c1 = xp[1 * 64], c2 = xp[2 * 64], c3 = xp[3 * 64];
  for (int tb = 0; tb < T_; tb += 4) {
    uint32_t n0 = xp[((tb + 4) & 511) * 64];  // wrapped tail reads are unused
    uint32_t n1 = xp[((tb + 5) & 511) * 64];
    uint32_t n2 = xp[((tb + 6) & 511) * 64];
    uint32_t n3 = xp[((tb + 7) & 511) * 64];
    step(c0, tb + 0);
    step(c1, tb + 1);
    step(c2, tb + 2);
    step(c3, tb + 3);
    c0 = n0; c1 = n1; c2 = n2; c3 = n3;
  }
}

// ---------------------------------------------------------------------------
// K3: attention (latent->score->softmax), pooled, decode. One block per batch.
// Reads fp32 h_t from the first 128B of each 256B xg slot.
// ---------------------------------------------------------------------------
__global__ void k3_attn(const uint32_t* __restrict__ xg,
                        const float* __restrict__ attnW, const float* __restrict__ attnB,
                        const float* __restrict__ attnU, const float* __restrict__ Wdec,
                        const float* __restrict__ bdec, float* __restrict__ out) {
  __shared__ float sW[H_ * H_];
  __shared__ float sU[H_], sB[H_];
  __shared__ float sSc[T_];
  __shared__ float sRed[8];
  __shared__ float sP[8][H_];
  const int tid = threadIdx.x;
  const int b = blockIdx.x;

  for (int i = tid; i < H_ * H_; i += 256) sW[i] = attnW[i];
  if (tid < H_) { sU[tid] = attnU[tid]; sB[tid] = attnB[tid]; }
  __syncthreads();

  const uint32_t* hbase = xg + (size_t)b * (T_ * 64);

  // phase 1: score_t = tanh(h_t @ attnW + attnB) . attnU   for t = tid, tid+256
  float mysc[2];
#pragma unroll
  for (int q = 0; q < 2; ++q) {
    int t = tid + q * 256;
    float hv[H_];
#pragma unroll
    for (int i = 0; i < 8; ++i)
      ((float4*)hv)[i] = ((const float4*)(hbase + (size_t)t * 64))[i];
    float lat[H_];
#pragma unroll
    for (int j = 0; j < H_; ++j) lat[j] = sB[j];
#pragma unroll
    for (int d = 0; d < H_; ++d) {
      float h0 = hv[d];
#pragma unroll
      for (int j4 = 0; j4 < 8; ++j4) {
        float4 w0 = *(const float4*)(&sW[d * H_ + j4 * 4]);
        lat[j4 * 4 + 0] += h0 * w0.x;
        lat[j4 * 4 + 1] += h0 * w0.y;
        lat[j4 * 4 + 2] += h0 * w0.z;
        lat[j4 * 4 + 3] += h0 * w0.w;
      }
    }
    float sc = 0.f;
#pragma unroll
    for (int j = 0; j < H_; ++j) sc += ftanh(lat[j]) * sU[j];
    mysc[q] = sc;
  }

  // softmax over T within the block
  float m2 = fmaxf(mysc[0], mysc[1]);
  m2 = fmaxf(m2, __shfl_xor(m2, 1));  m2 = fmaxf(m2, __shfl_xor(m2, 2));
  m2 = fmaxf(m2, __shfl_xor(m2, 4));  m2 = fmaxf(m2, __shfl_xor(m2, 8));
  m2 = fmaxf(m2, __shfl_xor(m2, 16)); m2 = fmaxf(m2, __shfl_xor(m2, 32));
  if ((tid & 63) == 0) sRed[tid >> 6] = m2;
  __syncthreads();
  float m = fmaxf(fmaxf(sRed[0], sRed[1]), fmaxf(sRed[2], sRed[3]));
  float e0 = __expf(mysc[0] - m), e1 = __expf(mysc[1] - m);
  sSc[tid] = e0;
  sSc[tid + 256] = e1;
  float s2 = e0 + e1;
  s2 += __shfl_xor(s2, 1);  s2 += __shfl_xor(s2, 2);
  s2 += __shfl_xor(s2, 4);  s2 += __shfl_xor(s2, 8);
  s2 += __shfl_xor(s2, 16); s2 += __shfl_xor(s2, 32);
  if ((tid & 63) == 0) sRed[4 + (tid >> 6)] = s2;
  __syncthreads();
  float l = (sRed[4] + sRed[5]) + (sRed[6] + sRed[7]);

  // phase 2: pooled[j] = sum_t e_t * h_t[j]; each 32-lane group covers 64 t's
  const int j = tid & 31;
  const int grp = tid >> 5;  // 0..7
  float p = 0.f;
  for (int tt = grp * 64; tt < grp * 64 + 64; ++tt) {
    p += sSc[tt] * ((const float*)(hbase + (size_t)tt * 64))[j];
  }
  sP[grp][j] = p;
  __syncthreads();

  if (tid < H_) {
    float pooled = 0.f;
#pragma unroll
    for (int g = 0; g < 8; ++g) pooled += sP[g][tid];
    pooled /= l;
    float h511 = ((const float*)(hbase + (size_t)511 * 64))[tid];
    float val = h511 * Wdec[tid] + pooled * Wdec[H_ + tid];
    val += __shfl_xor(val, 1);  val += __shfl_xor(val, 2);
    val += __shfl_xor(val, 4);  val += __shfl_xor(val, 8);
    val += __shfl_xor(val, 16);
    if (tid == 0) out[b] = fsig(val + bdec[0]);
  }
}

extern "C" void kernel_launch(void* const* d_in, const int* in_sizes, int n_in,
                              void* d_out, int out_size, void* d_ws, size_t ws_size,
                              hipStream_t stream) {
  const float* x     = (const float*)d_in[0];
  const float* Wenc  = (const float*)d_in[1];
  const float* benc  = (const float*)d_in[2];
  const float* kern  = (const float*)d_in[3];
  const float* rec   = (const float*)d_in[4];
  const float* bias  = (const float*)d_in[5];
  const float* attnW = (const float*)d_in[6];
  const float* attnB = (const float*)d_in[7];
  const float* attnU = (const float*)d_in[8];
  const float* Wdec  = (const float*)d_in[9];
  const float* bdec  = (const float*)d_in[10];

  uint32_t* xg = (uint32_t*)d_ws;  // [B][T][64] packed bf16 pairs = 128 MiB

  hipLaunchKernelGGL(k1_encxg, dim3((B_ * T_) / 256), dim3(256), 0, stream,
                     x, Wenc, benc, kern, bias, xg);
  hipLaunchKernelGGL(k2_scan, dim3(B_), dim3(64), 0, stream, xg, rec);
  hipLaunchKernelGGL(k3_attn, dim3(B_), dim3(256), 0, stream,
                     xg, attnW, attnB, attnU, Wdec, bdec, (float*)d_out);
}

// Round 5
// 1031.165 us; speedup vs baseline: 1.0786x; 1.0786x over previous
//
#include <hip/hip_runtime.h>
#include <stdint.h>

#define B_ 1024
#define T_ 512
#define F_ 64
#define H_ 32
#define G_ 128  // 4H

__device__ __forceinline__ uint32_t bf16r(float f) {
  uint32_t u = __builtin_bit_cast(uint32_t, f);
  return (u + 0x7fffu + ((u >> 16) & 1u)) >> 16;  // RNE bf16
}
__device__ __forceinline__ float rl(float v, int l) {
  return __builtin_bit_cast(float, __builtin_amdgcn_readlane(__builtin_bit_cast(int, v), l));
}
__device__ __forceinline__ float fsig(float x) { return 1.f / (1.f + __expf(-x)); }
__device__ __forceinline__ float ftanh(float x) { return 2.f / (1.f + __expf(-2.f * x)) - 1.f; }
__device__ __forceinline__ float bflo(uint32_t d) { return __builtin_bit_cast(float, d << 16); }
__device__ __forceinline__ float bfhi(uint32_t d) { return __builtin_bit_cast(float, d & 0xffff0000u); }

// ---------------------------------------------------------------------------
// K1 (rewritten): weights read from GLOBAL with wave-uniform addresses
// (backend emits s_load -> scalar pipe, no LDS instruction-throughput wall).
// LDS = one 16.4 KB chunked transposed x-tile, reused to park enc chunks.
// 8 blocks/CU resident (was 1).
// ---------------------------------------------------------------------------
__global__ __launch_bounds__(256, 1) void k1_encxg(
    const float* __restrict__ x, const float* __restrict__ Wenc,
    const float* __restrict__ benc, const float* __restrict__ kern,
    const float* __restrict__ bias, uint32_t* __restrict__ xg) {
  __shared__ float sX[16 * 257];  // [kk][row], 16.4 KB
  const int tid = threadIdx.x;
  const int r0 = blockIdx.x * 256;  // row = b*512 + t
  const int ri = tid >> 2;          // 0..63
  const int seg = tid & 3;          // which float4 of a 64B chunk

  float enc[F_];
#pragma unroll
  for (int j4 = 0; j4 < 16; ++j4) {
    float4 b = ((const float4*)benc)[j4];  // uniform -> s_load
    enc[j4 * 4 + 0] = b.x; enc[j4 * 4 + 1] = b.y;
    enc[j4 * 4 + 2] = b.z; enc[j4 * 4 + 3] = b.w;
  }

  // pass 1: enc = x @ W_enc (+bias), k chunked 4 x 16
#pragma unroll
  for (int c = 0; c < 4; ++c) {
    float4 v[4];
#pragma unroll
    for (int rr = 0; rr < 4; ++rr) {
      int row = rr * 64 + ri;
      v[rr] = *(const float4*)(x + (size_t)(r0 + row) * F_ + c * 16 + seg * 4);
    }
    __syncthreads();  // previous chunk fully consumed
#pragma unroll
    for (int rr = 0; rr < 4; ++rr) {
      int row = rr * 64 + ri;
      sX[(seg * 4 + 0) * 257 + row] = v[rr].x;
      sX[(seg * 4 + 1) * 257 + row] = v[rr].y;
      sX[(seg * 4 + 2) * 257 + row] = v[rr].z;
      sX[(seg * 4 + 3) * 257 + row] = v[rr].w;
    }
    __syncthreads();
#pragma unroll 2
    for (int kk = 0; kk < 16; ++kk) {
      float xk = sX[kk * 257 + tid];
      const float4* wr = (const float4*)(Wenc + (size_t)(c * 16 + kk) * F_);  // uniform -> s_load
#pragma unroll
      for (int j4 = 0; j4 < 16; ++j4) {
        float4 w = wr[j4];
        enc[j4 * 4 + 0] += xk * w.x; enc[j4 * 4 + 1] += xk * w.y;
        enc[j4 * 4 + 2] += xk * w.z; enc[j4 * 4 + 3] += xk * w.w;
      }
    }
  }
#pragma unroll
  for (int j = 0; j < F_; ++j) enc[j] = ftanh(enc[j]);

  // pass 2: acc = enc @ kernel (+bias), j chunked 4 x 16 via LDS park
  float acc[G_];
#pragma unroll
  for (int n4 = 0; n4 < 32; ++n4) {
    float4 b = ((const float4*)bias)[n4];  // uniform -> s_load
    acc[n4 * 4 + 0] = b.x; acc[n4 * 4 + 1] = b.y;
    acc[n4 * 4 + 2] = b.z; acc[n4 * 4 + 3] = b.w;
  }
#pragma unroll
  for (int c = 0; c < 4; ++c) {
    __syncthreads();
#pragma unroll
    for (int qq = 0; qq < 16; ++qq) sX[qq * 257 + tid] = enc[c * 16 + qq];
    __syncthreads();
#pragma unroll 2
    for (int j = 0; j < 16; ++j) {
      float e = sX[j * 257 + tid];
      const float4* kr = (const float4*)(kern + (size_t)(c * 16 + j) * G_);  // uniform -> s_load
#pragma unroll
      for (int n4 = 0; n4 < 32; ++n4) {
        float4 w = kr[n4];
        acc[n4 * 4 + 0] += e * w.x; acc[n4 * 4 + 1] += e * w.y;
        acc[n4 * 4 + 2] += e * w.z; acc[n4 * 4 + 3] += e * w.w;
      }
    }
  }

  // pack (n, n+64) pairs as bf16x2: scan lane j reads (z[j], z[j+64]) in one dword
  uint32_t* op = xg + (size_t)(r0 + tid) * 64;
#pragma unroll
  for (int q = 0; q < 16; ++q) {
    uint4 o;
    o.x = bf16r(acc[q * 4 + 0]) | (bf16r(acc[q * 4 + 0 + 64]) << 16);
    o.y = bf16r(acc[q * 4 + 1]) | (bf16r(acc[q * 4 + 1 + 64]) << 16);
    o.z = bf16r(acc[q * 4 + 2]) | (bf16r(acc[q * 4 + 2 + 64]) << 16);
    o.w = bf16r(acc[q * 4 + 3]) | (bf16r(acc[q * 4 + 3 + 64]) << 16);
    ((uint4*)op)[q] = o;
  }
}

// ---------------------------------------------------------------------------
// K2: LSTM scan. One wave per batch. 4-way split z accumulators; __shfl for
// f/o exchange. h_t (fp32) stored into the first 128B of the consumed 256B
// xg slot — through a SEPARATE __restrict__ pointer so the compiler does not
// serialize prefetch loads against the stores.
// ---------------------------------------------------------------------------
__global__ __launch_bounds__(64, 1) void k2_scan(
    const uint32_t* __restrict__ xgin, float* __restrict__ hout,
    const float* __restrict__ rec) {
  const int lane = threadIdx.x;
  const int b = blockIdx.x;
  const bool lo32 = (lane < 32);

  float rA[H_], rB[H_];
#pragma unroll
  for (int k = 0; k < H_; ++k) {
    rA[k] = rec[k * G_ + lane];        // columns 0..63   (i|f)
    rB[k] = rec[k * G_ + 64 + lane];   // columns 64..127 (g|o)
  }

  const uint32_t* xp = xgin + (size_t)b * (T_ * 64) + lane;
  float* hst = hout + (size_t)b * (T_ * 64);

  float h = 0.f, c = 0.f;

  auto step = [&](uint32_t w, int t) {
    float z1a = bflo(w);   // z[lane]       (i|f pre-act)
    float z2a = bfhi(w);   // z[lane+64]    (g|o pre-act)
    float z1b = 0.f, z1c = 0.f, z1d = 0.f;
    float z2b = 0.f, z2c = 0.f, z2d = 0.f;
#pragma unroll
    for (int k4 = 0; k4 < 8; ++k4) {
      float s0 = rl(h, 4 * k4 + 0);
      float s1 = rl(h, 4 * k4 + 1);
      float s2 = rl(h, 4 * k4 + 2);
      float s3 = rl(h, 4 * k4 + 3);
      z1a += s0 * rA[4 * k4 + 0];  z2a += s0 * rB[4 * k4 + 0];
      z1b += s1 * rA[4 * k4 + 1];  z2b += s1 * rB[4 * k4 + 1];
      z1c += s2 * rA[4 * k4 + 2];  z2c += s2 * rB[4 * k4 + 2];
      z1d += s3 * rA[4 * k4 + 3];  z2d += s3 * rB[4 * k4 + 3];
    }
    float z1 = (z1a + z1b) + (z1c + z1d);
    float z2 = (z2a + z2b) + (z2c + z2d);

    float act1 = fsig(z1);                       // i (lanes<32) | f (lanes>=32)
    float xx = lo32 ? 2.f * z2 : z2;
    float sg = fsig(xx);
    float act2 = lo32 ? 2.f * sg - 1.f : sg;     // tanh(g) | sigmoid(o)

    float f_all = __shfl(act1, lane | 32);       // f on all lanes (verified)
    float o_all = __shfl(act2, lane | 32);       // o on all lanes

    c = f_all * c + act1 * act2;                 // valid on lanes<32
    float tc = ftanh(c);
    h = o_all * tc;

    if (lo32) hst[(size_t)t * 64 + lane] = h;    // fp32 h into dead slot region
  };

  uint32_t c0 = xp[0 * 64], c1 = xp[1 * 64], c2 = xp[2 * 64], c3 = xp[3 * 64];
  for (int tb = 0; tb < T_; tb += 4) {
    uint32_t n0 = xp[((tb + 4) & 511) * 64];  // wrapped tail reads are unused
    uint32_t n1 = xp[((tb + 5) & 511) * 64];
    uint32_t n2 = xp[((tb + 6) & 511) * 64];
    uint32_t n3 = xp[((tb + 7) & 511) * 64];
    step(c0, tb + 0);
    step(c1, tb + 1);
    step(c2, tb + 2);
    step(c3, tb + 3);
    c0 = n0; c1 = n1; c2 = n2; c3 = n3;
  }
}

// ---------------------------------------------------------------------------
// K3: attention (latent->score->softmax), pooled, decode. One block per batch.
// Reads fp32 h_t from the first 128B of each 256B xg slot.
// ---------------------------------------------------------------------------
__global__ void k3_attn(const uint32_t* __restrict__ xg,
                        const float* __restrict__ attnW, const float* __restrict__ attnB,
                        const float* __restrict__ attnU, const float* __restrict__ Wdec,
                        const float* __restrict__ bdec, float* __restrict__ out) {
  __shared__ float sW[H_ * H_];
  __shared__ float sU[H_], sB[H_];
  __shared__ float sSc[T_];
  __shared__ float sRed[8];
  __shared__ float sP[8][H_];
  const int tid = threadIdx.x;
  const int b = blockIdx.x;

  for (int i = tid; i < H_ * H_; i += 256) sW[i] = attnW[i];
  if (tid < H_) { sU[tid] = attnU[tid]; sB[tid] = attnB[tid]; }
  __syncthreads();

  const uint32_t* hbase = xg + (size_t)b * (T_ * 64);

  // phase 1: score_t = tanh(h_t @ attnW + attnB) . attnU   for t = tid, tid+256
  float mysc[2];
#pragma unroll
  for (int q = 0; q < 2; ++q) {
    int t = tid + q * 256;
    float hv[H_];
#pragma unroll
    for (int i = 0; i < 8; ++i)
      ((float4*)hv)[i] = ((const float4*)(hbase + (size_t)t * 64))[i];
    float lat[H_];
#pragma unroll
    for (int j = 0; j < H_; ++j) lat[j] = sB[j];
#pragma unroll
    for (int d = 0; d < H_; ++d) {
      float h0 = hv[d];
#pragma unroll
      for (int j4 = 0; j4 < 8; ++j4) {
        float4 w0 = *(const float4*)(&sW[d * H_ + j4 * 4]);
        lat[j4 * 4 + 0] += h0 * w0.x;
        lat[j4 * 4 + 1] += h0 * w0.y;
        lat[j4 * 4 + 2] += h0 * w0.z;
        lat[j4 * 4 + 3] += h0 * w0.w;
      }
    }
    float sc = 0.f;
#pragma unroll
    for (int j = 0; j < H_; ++j) sc += ftanh(lat[j]) * sU[j];
    mysc[q] = sc;
  }

  // softmax over T within the block
  float m2 = fmaxf(mysc[0], mysc[1]);
  m2 = fmaxf(m2, __shfl_xor(m2, 1));  m2 = fmaxf(m2, __shfl_xor(m2, 2));
  m2 = fmaxf(m2, __shfl_xor(m2, 4));  m2 = fmaxf(m2, __shfl_xor(m2, 8));
  m2 = fmaxf(m2, __shfl_xor(m2, 16)); m2 = fmaxf(m2, __shfl_xor(m2, 32));
  if ((tid & 63) == 0) sRed[tid >> 6] = m2;
  __syncthreads();
  float m = fmaxf(fmaxf(sRed[0], sRed[1]), fmaxf(sRed[2], sRed[3]));
  float e0 = __expf(mysc[0] - m), e1 = __expf(mysc[1] - m);
  sSc[tid] = e0;
  sSc[tid + 256] = e1;
  float s2 = e0 + e1;
  s2 += __shfl_xor(s2, 1);  s2 += __shfl_xor(s2, 2);
  s2 += __shfl_xor(s2, 4);  s2 += __shfl_xor(s2, 8);
  s2 += __shfl_xor(s2, 16); s2 += __shfl_xor(s2, 32);
  if ((tid & 63) == 0) sRed[4 + (tid >> 6)] = s2;
  __syncthreads();
  float l = (sRed[4] + sRed[5]) + (sRed[6] + sRed[7]);

  // phase 2: pooled[j] = sum_t e_t * h_t[j]; each 32-lane group covers 64 t's
  const int j = tid & 31;
  const int grp = tid >> 5;  // 0..7
  float p = 0.f;
  for (int tt = grp * 64; tt < grp * 64 + 64; ++tt) {
    p += sSc[tt] * ((const float*)(hbase + (size_t)tt * 64))[j];
  }
  sP[grp][j] = p;
  __syncthreads();

  if (tid < H_) {
    float pooled = 0.f;
#pragma unroll
    for (int g = 0; g < 8; ++g) pooled += sP[g][tid];
    pooled /= l;
    float h511 = ((const float*)(hbase + (size_t)511 * 64))[tid];
    float val = h511 * Wdec[tid] + pooled * Wdec[H_ + tid];
    val += __shfl_xor(val, 1);  val += __shfl_xor(val, 2);
    val += __shfl_xor(val, 4);  val += __shfl_xor(val, 8);
    val += __shfl_xor(val, 16);
    if (tid == 0) out[b] = fsig(val + bdec[0]);
  }
}

extern "C" void kernel_launch(void* const* d_in, const int* in_sizes, int n_in,
                              void* d_out, int out_size, void* d_ws, size_t ws_size,
                              hipStream_t stream) {
  const float* x     = (const float*)d_in[0];
  const float* Wenc  = (const float*)d_in[1];
  const float* benc  = (const float*)d_in[2];
  const float* kern  = (const float*)d_in[3];
  const float* rec   = (const float*)d_in[4];
  const float* bias  = (const float*)d_in[5];
  const float* attnW = (const float*)d_in[6];
  const float* attnB = (const float*)d_in[7];
  const float* attnU = (const float*)d_in[8];
  const float* Wdec  = (const float*)d_in[9];
  const float* bdec  = (const float*)d_in[10];

  uint32_t* xg = (uint32_t*)d_ws;  // [B][T][64] packed bf16 pairs = 128 MiB

  hipLaunchKernelGGL(k1_encxg, dim3((B_ * T_) / 256), dim3(256), 0, stream,
                     x, Wenc, benc, kern, bias, xg);
  hipLaunchKernelGGL(k2_scan, dim3(B_), dim3(64), 0, stream,
                     xg, (float*)d_ws, rec);
  hipLaunchKernelGGL(k3_attn, dim3(B_), dim3(256), 0, stream,
                     xg, attnW, attnB, attnU, Wdec, bdec, (float*)d_out);
}

// Round 6
// 758.689 us; speedup vs baseline: 1.4659x; 1.3591x over previous
//
#include <hip/hip_runtime.h>
#include <stdint.h>

#define B_ 1024
#define T_ 512
#define F_ 64
#define H_ 32
#define G_ 128  // 4H

typedef __attribute__((ext_vector_type(8))) short bf16x8;
typedef __attribute__((ext_vector_type(4))) float f32x4;

__device__ __forceinline__ uint32_t bf16r(float f) {
  uint32_t u = __builtin_bit_cast(uint32_t, f);
  return (u + 0x7fffu + ((u >> 16) & 1u)) >> 16;  // RNE bf16
}
__device__ __forceinline__ float rl(float v, int l) {
  return __builtin_bit_cast(float, __builtin_amdgcn_readlane(__builtin_bit_cast(int, v), l));
}
__device__ __forceinline__ float fsig(float x) { return 1.f / (1.f + __expf(-x)); }
__device__ __forceinline__ float ftanh(float x) { return 2.f / (1.f + __expf(-2.f * x)) - 1.f; }
__device__ __forceinline__ float bflo(uint32_t d) { return __builtin_bit_cast(float, d << 16); }
__device__ __forceinline__ float bfhi(uint32_t d) { return __builtin_bit_cast(float, d & 0xffff0000u); }

#define MFMA16(a, b, c) __builtin_amdgcn_mfma_f32_16x16x32_bf16((a), (b), (c), 0, 0, 0)

// ---------------------------------------------------------------------------
// K1 (MFMA): xg = pack_bf16( tanh(x@Wenc + benc) @ kern + bias ).
// 256 threads (4 waves), 128 rows/block. Both GEMMs via mfma_f32_16x16x32_bf16.
// A and B fragments packed with the SAME k-map (k = kh*32 + (lane>>4)*8 + j),
// so any k-permutation vs HW cancels between A and B. C/D layout per m89:
// col = lane&15, row = (lane>>4)*4 + reg.
// ---------------------------------------------------------------------------
__global__ __launch_bounds__(256, 3) void k1_mfma(
    const float* __restrict__ x, const float* __restrict__ Wenc,
    const float* __restrict__ benc, const float* __restrict__ kern,
    const float* __restrict__ bias, uint32_t* __restrict__ xg) {
  __shared__ unsigned short sWt[64 * 72];   // Wenc^T bf16 [n][k], stride 72
  __shared__ unsigned short sKt[128 * 72];  // kern^T bf16 [n][k]
  __shared__ unsigned short sE[128 * 72];   // enc bf16 [row][k]
  const int tid = threadIdx.x;
  const int lane = tid & 63;
  const int w = tid >> 6;       // wave 0..3 -> rows w*32..w*32+31
  const int m = lane & 15;
  const int g = lane >> 4;      // 0..3
  const int r0 = blockIdx.x * 128;

  {  // stage Wenc^T and kern^T as bf16 (one-time)
    const int r = tid & 63;
    const int c0 = (tid >> 6) * 16;
#pragma unroll
    for (int q = 0; q < 4; ++q) {
      float4 v = *(const float4*)(Wenc + (size_t)r * F_ + c0 + q * 4);
      sWt[(c0 + q * 4 + 0) * 72 + r] = (unsigned short)bf16r(v.x);
      sWt[(c0 + q * 4 + 1) * 72 + r] = (unsigned short)bf16r(v.y);
      sWt[(c0 + q * 4 + 2) * 72 + r] = (unsigned short)bf16r(v.z);
      sWt[(c0 + q * 4 + 3) * 72 + r] = (unsigned short)bf16r(v.w);
    }
    const int d0 = (tid >> 6) * 32;
#pragma unroll
    for (int q = 0; q < 8; ++q) {
      float4 v = *(const float4*)(kern + (size_t)r * G_ + d0 + q * 4);
      sKt[(d0 + q * 4 + 0) * 72 + r] = (unsigned short)bf16r(v.x);
      sKt[(d0 + q * 4 + 1) * 72 + r] = (unsigned short)bf16r(v.y);
      sKt[(d0 + q * 4 + 2) * 72 + r] = (unsigned short)bf16r(v.z);
      sKt[(d0 + q * 4 + 3) * 72 + r] = (unsigned short)bf16r(v.w);
    }
  }
  __syncthreads();

  // A-fragments for GEMM1 straight from global x (rows r0+w*32+rt*16+m)
  bf16x8 a[2][2];
#pragma unroll
  for (int rt = 0; rt < 2; ++rt)
#pragma unroll
    for (int kh = 0; kh < 2; ++kh) {
      const float* xr = x + (size_t)(r0 + w * 32 + rt * 16 + m) * F_ + kh * 32 + g * 8;
      float4 v0 = ((const float4*)xr)[0];
      float4 v1 = ((const float4*)xr)[1];
      bf16x8 t;
      t[0] = (short)bf16r(v0.x); t[1] = (short)bf16r(v0.y);
      t[2] = (short)bf16r(v0.z); t[3] = (short)bf16r(v0.w);
      t[4] = (short)bf16r(v1.x); t[5] = (short)bf16r(v1.y);
      t[6] = (short)bf16r(v1.z); t[7] = (short)bf16r(v1.w);
      a[rt][kh] = t;
    }

  // GEMM1: enc = tanh(x @ Wenc + benc) -> sE
#pragma unroll
  for (int ct = 0; ct < 4; ++ct) {
    float be = benc[ct * 16 + m];
    f32x4 acc0 = {be, be, be, be};
    f32x4 acc1 = {be, be, be, be};
    bf16x8 b0 = *(const bf16x8*)&sWt[(ct * 16 + m) * 72 + g * 8];
    bf16x8 b1 = *(const bf16x8*)&sWt[(ct * 16 + m) * 72 + 32 + g * 8];
    acc0 = MFMA16(a[0][0], b0, acc0);
    acc0 = MFMA16(a[0][1], b1, acc0);
    acc1 = MFMA16(a[1][0], b0, acc1);
    acc1 = MFMA16(a[1][1], b1, acc1);
#pragma unroll
    for (int r4 = 0; r4 < 4; ++r4) {
      sE[(w * 32 + g * 4 + r4) * 72 + ct * 16 + m] =
          (unsigned short)bf16r(ftanh(acc0[r4]));
      sE[(w * 32 + 16 + g * 4 + r4) * 72 + ct * 16 + m] =
          (unsigned short)bf16r(ftanh(acc1[r4]));
    }
  }
  __syncthreads();

  // A-fragments for GEMM2 from sE
  bf16x8 e[2][2];
#pragma unroll
  for (int rt = 0; rt < 2; ++rt)
#pragma unroll
    for (int kh = 0; kh < 2; ++kh)
      e[rt][kh] = *(const bf16x8*)&sE[(w * 32 + rt * 16 + m) * 72 + kh * 32 + g * 8];

  // GEMM2 + bias + bf16 pair-pack (col n pairs with n+64)
#pragma unroll
  for (int ctp = 0; ctp < 4; ++ctp) {
    float blo = bias[ctp * 16 + m];
    float bhi = bias[64 + ctp * 16 + m];
    f32x4 lo0 = {blo, blo, blo, blo}, lo1 = {blo, blo, blo, blo};
    f32x4 hi0 = {bhi, bhi, bhi, bhi}, hi1 = {bhi, bhi, bhi, bhi};
    bf16x8 bl0 = *(const bf16x8*)&sKt[(ctp * 16 + m) * 72 + g * 8];
    bf16x8 bl1 = *(const bf16x8*)&sKt[(ctp * 16 + m) * 72 + 32 + g * 8];
    bf16x8 bh0 = *(const bf16x8*)&sKt[(64 + ctp * 16 + m) * 72 + g * 8];
    bf16x8 bh1 = *(const bf16x8*)&sKt[(64 + ctp * 16 + m) * 72 + 32 + g * 8];
    lo0 = MFMA16(e[0][0], bl0, lo0);  lo0 = MFMA16(e[0][1], bl1, lo0);
    lo1 = MFMA16(e[1][0], bl0, lo1);  lo1 = MFMA16(e[1][1], bl1, lo1);
    hi0 = MFMA16(e[0][0], bh0, hi0);  hi0 = MFMA16(e[0][1], bh1, hi0);
    hi1 = MFMA16(e[1][0], bh0, hi1);  hi1 = MFMA16(e[1][1], bh1, hi1);
#pragma unroll
    for (int r4 = 0; r4 < 4; ++r4) {
      int row0 = r0 + w * 32 + g * 4 + r4;
      xg[(size_t)row0 * 64 + ctp * 16 + m] =
          bf16r(lo0[r4]) | (bf16r(hi0[r4]) << 16);
      int row1 = row0 + 16;
      xg[(size_t)row1 * 64 + ctp * 16 + m] =
          bf16r(lo1[r4]) | (bf16r(hi1[r4]) << 16);
    }
  }
}

// ---------------------------------------------------------------------------
// K2: LSTM scan. One wave per batch. 8-deep xg prefetch (1 wave/SIMD => no
// TLP; ILP depth must cover ~900cyc HBM latency). 4-way split z accumulators;
// __shfl for f/o exchange; fp32 h into first 128B of the consumed xg slot.
// ---------------------------------------------------------------------------
__global__ __launch_bounds__(64, 1) void k2_scan(
    const uint32_t* __restrict__ xgin, float* __restrict__ hout,
    const float* __restrict__ rec) {
  const int lane = threadIdx.x;
  const int b = blockIdx.x;
  const bool lo32 = (lane < 32);

  float rA[H_], rB[H_];
#pragma unroll
  for (int k = 0; k < H_; ++k) {
    rA[k] = rec[k * G_ + lane];        // columns 0..63   (i|f)
    rB[k] = rec[k * G_ + 64 + lane];   // columns 64..127 (g|o)
  }

  const uint32_t* xp = xgin + (size_t)b * (T_ * 64) + lane;
  float* hst = hout + (size_t)b * (T_ * 64);

  float h = 0.f, c = 0.f;

  auto step = [&](uint32_t w, int t) {
    float z1a = bflo(w);   // z[lane]       (i|f pre-act)
    float z2a = bfhi(w);   // z[lane+64]    (g|o pre-act)
    float z1b = 0.f, z1c = 0.f, z1d = 0.f;
    float z2b = 0.f, z2c = 0.f, z2d = 0.f;
#pragma unroll
    for (int k4 = 0; k4 < 8; ++k4) {
      float s0 = rl(h, 4 * k4 + 0);
      float s1 = rl(h, 4 * k4 + 1);
      float s2 = rl(h, 4 * k4 + 2);
      float s3 = rl(h, 4 * k4 + 3);
      z1a += s0 * rA[4 * k4 + 0];  z2a += s0 * rB[4 * k4 + 0];
      z1b += s1 * rA[4 * k4 + 1];  z2b += s1 * rB[4 * k4 + 1];
      z1c += s2 * rA[4 * k4 + 2];  z2c += s2 * rB[4 * k4 + 2];
      z1d += s3 * rA[4 * k4 + 3];  z2d += s3 * rB[4 * k4 + 3];
    }
    float z1 = (z1a + z1b) + (z1c + z1d);
    float z2 = (z2a + z2b) + (z2c + z2d);

    float act1 = fsig(z1);                       // i (lanes<32) | f (lanes>=32)
    float xx = lo32 ? 2.f * z2 : z2;
    float sg = fsig(xx);
    float act2 = lo32 ? 2.f * sg - 1.f : sg;     // tanh(g) | sigmoid(o)

    float f_all = __shfl(act1, lane | 32);       // f on all lanes (verified)
    float o_all = __shfl(act2, lane | 32);       // o on all lanes

    c = f_all * c + act1 * act2;                 // valid on lanes<32
    float tc = ftanh(c);
    h = o_all * tc;

    if (lo32) hst[(size_t)t * 64 + lane] = h;    // fp32 h into dead slot region
  };

  uint32_t p[8];
#pragma unroll
  for (int i = 0; i < 8; ++i) p[i] = xp[i * 64];
  for (int tb = 0; tb < T_; tb += 8) {
    uint32_t n[8];
#pragma unroll
    for (int i = 0; i < 8; ++i) n[i] = xp[((tb + 8 + i) & 511) * 64];  // tail wrap unused
#pragma unroll
    for (int i = 0; i < 8; ++i) step(p[i], tb + i);
#pragma unroll
    for (int i = 0; i < 8; ++i) p[i] = n[i];
  }
}

// ---------------------------------------------------------------------------
// K3: attention (latent->score->softmax), pooled, decode. One block per batch.
// UNCHANGED from round 4/5 (will become visible in top-5 once k1 drops).
// ---------------------------------------------------------------------------
__global__ void k3_attn(const uint32_t* __restrict__ xg,
                        const float* __restrict__ attnW, const float* __restrict__ attnB,
                        const float* __restrict__ attnU, const float* __restrict__ Wdec,
                        const float* __restrict__ bdec, float* __restrict__ out) {
  __shared__ float sW[H_ * H_];
  __shared__ float sU[H_], sB[H_];
  __shared__ float sSc[T_];
  __shared__ float sRed[8];
  __shared__ float sP[8][H_];
  const int tid = threadIdx.x;
  const int b = blockIdx.x;

  for (int i = tid; i < H_ * H_; i += 256) sW[i] = attnW[i];
  if (tid < H_) { sU[tid] = attnU[tid]; sB[tid] = attnB[tid]; }
  __syncthreads();

  const uint32_t* hbase = xg + (size_t)b * (T_ * 64);

  float mysc[2];
#pragma unroll
  for (int q = 0; q < 2; ++q) {
    int t = tid + q * 256;
    float hv[H_];
#pragma unroll
    for (int i = 0; i < 8; ++i)
      ((float4*)hv)[i] = ((const float4*)(hbase + (size_t)t * 64))[i];
    float lat[H_];
#pragma unroll
    for (int j = 0; j < H_; ++j) lat[j] = sB[j];
#pragma unroll
    for (int d = 0; d < H_; ++d) {
      float h0 = hv[d];
#pragma unroll
      for (int j4 = 0; j4 < 8; ++j4) {
        float4 w0 = *(const float4*)(&sW[d * H_ + j4 * 4]);
        lat[j4 * 4 + 0] += h0 * w0.x;
        lat[j4 * 4 + 1] += h0 * w0.y;
        lat[j4 * 4 + 2] += h0 * w0.z;
        lat[j4 * 4 + 3] += h0 * w0.w;
      }
    }
    float sc = 0.f;
#pragma unroll
    for (int j = 0; j < H_; ++j) sc += ftanh(lat[j]) * sU[j];
    mysc[q] = sc;
  }

  float m2 = fmaxf(mysc[0], mysc[1]);
  m2 = fmaxf(m2, __shfl_xor(m2, 1));  m2 = fmaxf(m2, __shfl_xor(m2, 2));
  m2 = fmaxf(m2, __shfl_xor(m2, 4));  m2 = fmaxf(m2, __shfl_xor(m2, 8));
  m2 = fmaxf(m2, __shfl_xor(m2, 16)); m2 = fmaxf(m2, __shfl_xor(m2, 32));
  if ((tid & 63) == 0) sRed[tid >> 6] = m2;
  __syncthreads();
  float m = fmaxf(fmaxf(sRed[0], sRed[1]), fmaxf(sRed[2], sRed[3]));
  float e0 = __expf(mysc[0] - m), e1 = __expf(mysc[1] - m);
  sSc[tid] = e0;
  sSc[tid + 256] = e1;
  float s2 = e0 + e1;
  s2 += __shfl_xor(s2, 1);  s2 += __shfl_xor(s2, 2);
  s2 += __shfl_xor(s2, 4);  s2 += __shfl_xor(s2, 8);
  s2 += __shfl_xor(s2, 16); s2 += __shfl_xor(s2, 32);
  if ((tid & 63) == 0) sRed[4 + (tid >> 6)] = s2;
  __syncthreads();
  float l = (sRed[4] + sRed[5]) + (sRed[6] + sRed[7]);

  const int j = tid & 31;
  const int grp = tid >> 5;  // 0..7
  float p = 0.f;
  for (int tt = grp * 64; tt < grp * 64 + 64; ++tt) {
    p += sSc[tt] * ((const float*)(hbase + (size_t)tt * 64))[j];
  }
  sP[grp][j] = p;
  __syncthreads();

  if (tid < H_) {
    float pooled = 0.f;
#pragma unroll
    for (int g = 0; g < 8; ++g) pooled += sP[g][tid];
    pooled /= l;
    float h511 = ((const float*)(hbase + (size_t)511 * 64))[tid];
    float val = h511 * Wdec[tid] + pooled * Wdec[H_ + tid];
    val += __shfl_xor(val, 1);  val += __shfl_xor(val, 2);
    val += __shfl_xor(val, 4);  val += __shfl_xor(val, 8);
    val += __shfl_xor(val, 16);
    if (tid == 0) out[b] = fsig(val + bdec[0]);
  }
}

extern "C" void kernel_launch(void* const* d_in, const int* in_sizes, int n_in,
                              void* d_out, int out_size, void* d_ws, size_t ws_size,
                              hipStream_t stream) {
  const float* x     = (const float*)d_in[0];
  const float* Wenc  = (const float*)d_in[1];
  const float* benc  = (const float*)d_in[2];
  const float* kern  = (const float*)d_in[3];
  const float* rec   = (const float*)d_in[4];
  const float* bias  = (const float*)d_in[5];
  const float* attnW = (const float*)d_in[6];
  const float* attnB = (const float*)d_in[7];
  const float* attnU = (const float*)d_in[8];
  const float* Wdec  = (const float*)d_in[9];
  const float* bdec  = (const float*)d_in[10];

  uint32_t* xg = (uint32_t*)d_ws;  // [B][T][64] packed bf16 pairs = 128 MiB

  hipLaunchKernelGGL(k1_mfma, dim3((B_ * T_) / 128), dim3(256), 0, stream,
                     x, Wenc, benc, kern, bias, xg);
  hipLaunchKernelGGL(k2_scan, dim3(B_), dim3(64), 0, stream,
                     xg, (float*)d_ws, rec);
  hipLaunchKernelGGL(k3_attn, dim3(B_), dim3(256), 0, stream,
                     xg, attnW, attnB, attnU, Wdec, bdec, (float*)d_out);
}

// Round 7
// 421.041 us; speedup vs baseline: 2.6415x; 1.8019x over previous
//
#include <hip/hip_runtime.h>
#include <stdint.h>

#define B_ 1024
#define T_ 512
#define F_ 64
#define H_ 32
#define G_ 128  // 4H

typedef __attribute__((ext_vector_type(8))) short bf16x8;
typedef __attribute__((ext_vector_type(4))) float f32x4;

__device__ __forceinline__ uint32_t bf16r(float f) {
  uint32_t u = __builtin_bit_cast(uint32_t, f);
  return (u + 0x7fffu + ((u >> 16) & 1u)) >> 16;  // RNE bf16
}
__device__ __forceinline__ float rl(float v, int l) {
  return __builtin_bit_cast(float, __builtin_amdgcn_readlane(__builtin_bit_cast(int, v), l));
}
__device__ __forceinline__ float fsig(float x) { return 1.f / (1.f + __expf(-x)); }
__device__ __forceinline__ float ftanh(float x) { return 2.f / (1.f + __expf(-2.f * x)) - 1.f; }
__device__ __forceinline__ float bflo(uint32_t d) { return __builtin_bit_cast(float, d << 16); }
__device__ __forceinline__ float bfhi(uint32_t d) { return __builtin_bit_cast(float, d & 0xffff0000u); }

#define MFMA16(a, b, c) __builtin_amdgcn_mfma_f32_16x16x32_bf16((a), (b), (c), 0, 0, 0)

// ---------------------------------------------------------------------------
// K1 (MFMA, unchanged from round 6): xg = pack_bf16(tanh(x@Wenc+benc)@kern+bias)
// ---------------------------------------------------------------------------
__global__ __launch_bounds__(256, 3) void k1_mfma(
    const float* __restrict__ x, const float* __restrict__ Wenc,
    const float* __restrict__ benc, const float* __restrict__ kern,
    const float* __restrict__ bias, uint32_t* __restrict__ xg) {
  __shared__ unsigned short sWt[64 * 72];   // Wenc^T bf16 [n][k], stride 72
  __shared__ unsigned short sKt[128 * 72];  // kern^T bf16 [n][k]
  __shared__ unsigned short sE[128 * 72];   // enc bf16 [row][k]
  const int tid = threadIdx.x;
  const int lane = tid & 63;
  const int w = tid >> 6;       // wave 0..3 -> rows w*32..w*32+31
  const int m = lane & 15;
  const int g = lane >> 4;      // 0..3
  const int r0 = blockIdx.x * 128;

  {  // stage Wenc^T and kern^T as bf16 (one-time)
    const int r = tid & 63;
    const int c0 = (tid >> 6) * 16;
#pragma unroll
    for (int q = 0; q < 4; ++q) {
      float4 v = *(const float4*)(Wenc + (size_t)r * F_ + c0 + q * 4);
      sWt[(c0 + q * 4 + 0) * 72 + r] = (unsigned short)bf16r(v.x);
      sWt[(c0 + q * 4 + 1) * 72 + r] = (unsigned short)bf16r(v.y);
      sWt[(c0 + q * 4 + 2) * 72 + r] = (unsigned short)bf16r(v.z);
      sWt[(c0 + q * 4 + 3) * 72 + r] = (unsigned short)bf16r(v.w);
    }
    const int d0 = (tid >> 6) * 32;
#pragma unroll
    for (int q = 0; q < 8; ++q) {
      float4 v = *(const float4*)(kern + (size_t)r * G_ + d0 + q * 4);
      sKt[(d0 + q * 4 + 0) * 72 + r] = (unsigned short)bf16r(v.x);
      sKt[(d0 + q * 4 + 1) * 72 + r] = (unsigned short)bf16r(v.y);
      sKt[(d0 + q * 4 + 2) * 72 + r] = (unsigned short)bf16r(v.z);
      sKt[(d0 + q * 4 + 3) * 72 + r] = (unsigned short)bf16r(v.w);
    }
  }
  __syncthreads();

  // A-fragments for GEMM1 straight from global x (rows r0+w*32+rt*16+m)
  bf16x8 a[2][2];
#pragma unroll
  for (int rt = 0; rt < 2; ++rt)
#pragma unroll
    for (int kh = 0; kh < 2; ++kh) {
      const float* xr = x + (size_t)(r0 + w * 32 + rt * 16 + m) * F_ + kh * 32 + g * 8;
      float4 v0 = ((const float4*)xr)[0];
      float4 v1 = ((const float4*)xr)[1];
      bf16x8 t;
      t[0] = (short)bf16r(v0.x); t[1] = (short)bf16r(v0.y);
      t[2] = (short)bf16r(v0.z); t[3] = (short)bf16r(v0.w);
      t[4] = (short)bf16r(v1.x); t[5] = (short)bf16r(v1.y);
      t[6] = (short)bf16r(v1.z); t[7] = (short)bf16r(v1.w);
      a[rt][kh] = t;
    }

  // GEMM1: enc = tanh(x @ Wenc + benc) -> sE
#pragma unroll
  for (int ct = 0; ct < 4; ++ct) {
    float be = benc[ct * 16 + m];
    f32x4 acc0 = {be, be, be, be};
    f32x4 acc1 = {be, be, be, be};
    bf16x8 b0 = *(const bf16x8*)&sWt[(ct * 16 + m) * 72 + g * 8];
    bf16x8 b1 = *(const bf16x8*)&sWt[(ct * 16 + m) * 72 + 32 + g * 8];
    acc0 = MFMA16(a[0][0], b0, acc0);
    acc0 = MFMA16(a[0][1], b1, acc0);
    acc1 = MFMA16(a[1][0], b0, acc1);
    acc1 = MFMA16(a[1][1], b1, acc1);
#pragma unroll
    for (int r4 = 0; r4 < 4; ++r4) {
      sE[(w * 32 + g * 4 + r4) * 72 + ct * 16 + m] =
          (unsigned short)bf16r(ftanh(acc0[r4]));
      sE[(w * 32 + 16 + g * 4 + r4) * 72 + ct * 16 + m] =
          (unsigned short)bf16r(ftanh(acc1[r4]));
    }
  }
  __syncthreads();

  // A-fragments for GEMM2 from sE
  bf16x8 e[2][2];
#pragma unroll
  for (int rt = 0; rt < 2; ++rt)
#pragma unroll
    for (int kh = 0; kh < 2; ++kh)
      e[rt][kh] = *(const bf16x8*)&sE[(w * 32 + rt * 16 + m) * 72 + kh * 32 + g * 8];

  // GEMM2 + bias + bf16 pair-pack (col n pairs with n+64)
#pragma unroll
  for (int ctp = 0; ctp < 4; ++ctp) {
    float blo = bias[ctp * 16 + m];
    float bhi = bias[64 + ctp * 16 + m];
    f32x4 lo0 = {blo, blo, blo, blo}, lo1 = {blo, blo, blo, blo};
    f32x4 hi0 = {bhi, bhi, bhi, bhi}, hi1 = {bhi, bhi, bhi, bhi};
    bf16x8 bl0 = *(const bf16x8*)&sKt[(ctp * 16 + m) * 72 + g * 8];
    bf16x8 bl1 = *(const bf16x8*)&sKt[(ctp * 16 + m) * 72 + 32 + g * 8];
    bf16x8 bh0 = *(const bf16x8*)&sKt[(64 + ctp * 16 + m) * 72 + g * 8];
    bf16x8 bh1 = *(const bf16x8*)&sKt[(64 + ctp * 16 + m) * 72 + 32 + g * 8];
    lo0 = MFMA16(e[0][0], bl0, lo0);  lo0 = MFMA16(e[0][1], bl1, lo0);
    lo1 = MFMA16(e[1][0], bl0, lo1);  lo1 = MFMA16(e[1][1], bl1, lo1);
    hi0 = MFMA16(e[0][0], bh0, hi0);  hi0 = MFMA16(e[0][1], bh1, hi0);
    hi1 = MFMA16(e[1][0], bh0, hi1);  hi1 = MFMA16(e[1][1], bh1, hi1);
#pragma unroll
    for (int r4 = 0; r4 < 4; ++r4) {
      int row0 = r0 + w * 32 + g * 4 + r4;
      xg[(size_t)row0 * 64 + ctp * 16 + m] =
          bf16r(lo0[r4]) | (bf16r(hi0[r4]) << 16);
      int row1 = row0 + 16;
      xg[(size_t)row1 * 64 + ctp * 16 + m] =
          bf16r(lo1[r4]) | (bf16r(hi1[r4]) << 16);
    }
  }
}

// ---------------------------------------------------------------------------
// K2 (unchanged from round 6): LSTM scan, one wave per batch, 8-deep prefetch.
// ---------------------------------------------------------------------------
__global__ __launch_bounds__(64, 1) void k2_scan(
    const uint32_t* __restrict__ xgin, float* __restrict__ hout,
    const float* __restrict__ rec) {
  const int lane = threadIdx.x;
  const int b = blockIdx.x;
  const bool lo32 = (lane < 32);

  float rA[H_], rB[H_];
#pragma unroll
  for (int k = 0; k < H_; ++k) {
    rA[k] = rec[k * G_ + lane];        // columns 0..63   (i|f)
    rB[k] = rec[k * G_ + 64 + lane];   // columns 64..127 (g|o)
  }

  const uint32_t* xp = xgin + (size_t)b * (T_ * 64) + lane;
  float* hst = hout + (size_t)b * (T_ * 64);

  float h = 0.f, c = 0.f;

  auto step = [&](uint32_t w, int t) {
    float z1a = bflo(w);   // z[lane]       (i|f pre-act)
    float z2a = bfhi(w);   // z[lane+64]    (g|o pre-act)
    float z1b = 0.f, z1c = 0.f, z1d = 0.f;
    float z2b = 0.f, z2c = 0.f, z2d = 0.f;
#pragma unroll
    for (int k4 = 0; k4 < 8; ++k4) {
      float s0 = rl(h, 4 * k4 + 0);
      float s1 = rl(h, 4 * k4 + 1);
      float s2 = rl(h, 4 * k4 + 2);
      float s3 = rl(h, 4 * k4 + 3);
      z1a += s0 * rA[4 * k4 + 0];  z2a += s0 * rB[4 * k4 + 0];
      z1b += s1 * rA[4 * k4 + 1];  z2b += s1 * rB[4 * k4 + 1];
      z1c += s2 * rA[4 * k4 + 2];  z2c += s2 * rB[4 * k4 + 2];
      z1d += s3 * rA[4 * k4 + 3];  z2d += s3 * rB[4 * k4 + 3];
    }
    float z1 = (z1a + z1b) + (z1c + z1d);
    float z2 = (z2a + z2b) + (z2c + z2d);

    float act1 = fsig(z1);                       // i (lanes<32) | f (lanes>=32)
    float xx = lo32 ? 2.f * z2 : z2;
    float sg = fsig(xx);
    float act2 = lo32 ? 2.f * sg - 1.f : sg;     // tanh(g) | sigmoid(o)

    float f_all = __shfl(act1, lane | 32);       // f on all lanes (verified)
    float o_all = __shfl(act2, lane | 32);       // o on all lanes

    c = f_all * c + act1 * act2;                 // valid on lanes<32
    float tc = ftanh(c);
    h = o_all * tc;

    if (lo32) hst[(size_t)t * 64 + lane] = h;    // fp32 h into dead slot region
  };

  uint32_t p[8];
#pragma unroll
  for (int i = 0; i < 8; ++i) p[i] = xp[i * 64];
  for (int tb = 0; tb < T_; tb += 8) {
    uint32_t n[8];
#pragma unroll
    for (int i = 0; i < 8; ++i) n[i] = xp[((tb + 8 + i) & 511) * 64];  // tail wrap unused
#pragma unroll
    for (int i = 0; i < 8; ++i) step(p[i], tb + i);
#pragma unroll
    for (int i = 0; i < 8; ++i) p[i] = n[i];
  }
}

// ---------------------------------------------------------------------------
// K3 (rewritten, spill-free): attention scores, softmax, pooled, decode.
// No local array is addressed through a cast (SROA-safe fills); attnW/attnB/
// attnU read from global with wave-uniform addresses -> s_load (scalar pipe).
// ---------------------------------------------------------------------------
__global__ __launch_bounds__(256, 4) void k3_attn(
    const uint32_t* __restrict__ xg,
    const float* __restrict__ attnW, const float* __restrict__ attnB,
    const float* __restrict__ attnU, const float* __restrict__ Wdec,
    const float* __restrict__ bdec, float* __restrict__ out) {
  __shared__ float sSc[T_];
  __shared__ float sRed[8];
  __shared__ float sP[8][H_];
  const int tid = threadIdx.x;
  const int b = blockIdx.x;

  const uint32_t* hbase = xg + (size_t)b * (T_ * 64);

  // phase 1: score_t = tanh(h_t @ attnW + attnB) . attnU   for t = tid, tid+256
  float mysc[2];
#pragma unroll
  for (int q = 0; q < 2; ++q) {
    int t = tid + q * 256;
    const float4* hp = (const float4*)(hbase + (size_t)t * 64);

    float hv[H_];  // filled via float4 temps, scalar-indexed stores (SROA-safe)
#pragma unroll
    for (int i = 0; i < 8; ++i) {
      float4 v = hp[i];
      hv[4 * i + 0] = v.x; hv[4 * i + 1] = v.y;
      hv[4 * i + 2] = v.z; hv[4 * i + 3] = v.w;
    }

    float lat[H_];
#pragma unroll
    for (int j4 = 0; j4 < 8; ++j4) {
      float4 bv = ((const float4*)attnB)[j4];  // uniform -> s_load
      lat[4 * j4 + 0] = bv.x; lat[4 * j4 + 1] = bv.y;
      lat[4 * j4 + 2] = bv.z; lat[4 * j4 + 3] = bv.w;
    }
#pragma unroll
    for (int d = 0; d < H_; ++d) {
      float hd = hv[d];
      const float4* wr = (const float4*)(attnW + d * H_);  // uniform -> s_load
#pragma unroll
      for (int j4 = 0; j4 < 8; ++j4) {
        float4 w = wr[j4];
        lat[4 * j4 + 0] += hd * w.x;
        lat[4 * j4 + 1] += hd * w.y;
        lat[4 * j4 + 2] += hd * w.z;
        lat[4 * j4 + 3] += hd * w.w;
      }
    }
    float sc = 0.f;
#pragma unroll
    for (int j = 0; j < H_; ++j) sc += ftanh(lat[j]) * attnU[j];  // u: s_load
    mysc[q] = sc;
  }

  // softmax over T within the block
  float m2 = fmaxf(mysc[0], mysc[1]);
  m2 = fmaxf(m2, __shfl_xor(m2, 1));  m2 = fmaxf(m2, __shfl_xor(m2, 2));
  m2 = fmaxf(m2, __shfl_xor(m2, 4));  m2 = fmaxf(m2, __shfl_xor(m2, 8));
  m2 = fmaxf(m2, __shfl_xor(m2, 16)); m2 = fmaxf(m2, __shfl_xor(m2, 32));
  if ((tid & 63) == 0) sRed[tid >> 6] = m2;
  __syncthreads();
  float m = fmaxf(fmaxf(sRed[0], sRed[1]), fmaxf(sRed[2], sRed[3]));
  float e0 = __expf(mysc[0] - m), e1 = __expf(mysc[1] - m);
  sSc[tid] = e0;
  sSc[tid + 256] = e1;
  float s2 = e0 + e1;
  s2 += __shfl_xor(s2, 1);  s2 += __shfl_xor(s2, 2);
  s2 += __shfl_xor(s2, 4);  s2 += __shfl_xor(s2, 8);
  s2 += __shfl_xor(s2, 16); s2 += __shfl_xor(s2, 32);
  if ((tid & 63) == 0) sRed[4 + (tid >> 6)] = s2;
  __syncthreads();
  float l = (sRed[4] + sRed[5]) + (sRed[6] + sRed[7]);

  // phase 2: pooled[j] = sum_t e_t * h_t[j]; each 32-lane group covers 64 t's
  const int j = tid & 31;
  const int grp = tid >> 5;  // 0..7
  float p = 0.f;
  for (int tt = grp * 64; tt < grp * 64 + 64; ++tt) {
    p += sSc[tt] * ((const float*)(hbase + (size_t)tt * 64))[j];
  }
  sP[grp][j] = p;
  __syncthreads();

  if (tid < H_) {
    float pooled = 0.f;
#pragma unroll
    for (int g = 0; g < 8; ++g) pooled += sP[g][tid];
    pooled /= l;
    float h511 = ((const float*)(hbase + (size_t)511 * 64))[tid];
    float val = h511 * Wdec[tid] + pooled * Wdec[H_ + tid];
    val += __shfl_xor(val, 1);  val += __shfl_xor(val, 2);
    val += __shfl_xor(val, 4);  val += __shfl_xor(val, 8);
    val += __shfl_xor(val, 16);
    if (tid == 0) out[b] = fsig(val + bdec[0]);
  }
}

extern "C" void kernel_launch(void* const* d_in, const int* in_sizes, int n_in,
                              void* d_out, int out_size, void* d_ws, size_t ws_size,
                              hipStream_t stream) {
  const float* x     = (const float*)d_in[0];
  const float* Wenc  = (const float*)d_in[1];
  const float* benc  = (const float*)d_in[2];
  const float* kern  = (const float*)d_in[3];
  const float* rec   = (const float*)d_in[4];
  const float* bias  = (const float*)d_in[5];
  const float* attnW = (const float*)d_in[6];
  const float* attnB = (const float*)d_in[7];
  const float* attnU = (const float*)d_in[8];
  const float* Wdec  = (const float*)d_in[9];
  const float* bdec  = (const float*)d_in[10];

  uint32_t* xg = (uint32_t*)d_ws;  // [B][T][64] packed bf16 pairs = 128 MiB

  hipLaunchKernelGGL(k1_mfma, dim3((B_ * T_) / 128), dim3(256), 0, stream,
                     x, Wenc, benc, kern, bias, xg);
  hipLaunchKernelGGL(k2_scan, dim3(B_), dim3(64), 0, stream,
                     xg, (float*)d_ws, rec);
  hipLaunchKernelGGL(k3_attn, dim3(B_), dim3(256), 0, stream,
                     xg, attnW, attnB, attnU, Wdec, bdec, (float*)d_out);
}